// Round 3
// baseline (136.436 us; speedup 1.0000x reference)
//
#include <hip/hip_runtime.h>

#define TT 8
#define NN 2048
#define SS 8192
#define MM (NN * SS)   // 16777216 elements

// Bernoulli integer thresholds: p * 2^23 (all probabilities are dyadic k/128)
#define TH_CAP10  655360u    // 10/128 * 2^23  (ucapture, uminus)
#define TH_SEARCH 65536u     //  1/128 * 2^23
#define TH_BACK   6291456u   // 96/128 * 2^23
#define TH_MIN    262144u    //  4/128 * 2^23

#define NBLOCKS   2048
#define NTHREADS  (NBLOCKS * 256)        // 524288
#define ITERS     (MM / 4 / NTHREADS)    // 8 tiles of 4 elements per thread

typedef int   __attribute__((ext_vector_type(4))) intx4;
typedef float __attribute__((ext_vector_type(4))) floatx4;
typedef unsigned __attribute__((ext_vector_type(4))) uintx4;

// 4 branch-config rows x 8 words: {ka0,ka1, kb0,kb1, kc0,kc1, thB, sgn_bits}
struct Tbl { unsigned v[32]; };

__host__ __device__ __forceinline__ void tf2x32(unsigned k0, unsigned k1,
                                                unsigned x0, unsigned x1,
                                                unsigned& o0, unsigned& o1) {
  const unsigned ks2 = k0 ^ k1 ^ 0x1BD11BDAu;
  x0 += k0; x1 += k1;
#define TFR(r) { x0 += x1; x1 = (x1 << (r)) | (x1 >> (32 - (r))); x1 ^= x0; }
  TFR(13) TFR(15) TFR(26) TFR(6)
  x0 += k1;  x1 += ks2 + 1u;
  TFR(17) TFR(29) TFR(16) TFR(24)
  x0 += ks2; x1 += k0 + 2u;
  TFR(13) TFR(15) TFR(26) TFR(6)
  x0 += k0;  x1 += k1 + 3u;
  TFR(17) TFR(29) TFR(16) TFR(24)
  x0 += k1;  x1 += ks2 + 4u;
  TFR(13) TFR(15) TFR(26) TFR(6)
  x0 += ks2; x1 += k0 + 5u;
#undef TFR
  o0 = x0; o1 = x1;
}

// Pre-kernel: per-row output spike count (2048 rows) into d_ws.
__global__ __launch_bounds__(256) void ModSTDP_ocnt_kernel(
    const int* __restrict__ outS, int* __restrict__ ocnt) {
  const int n = blockIdx.x * blockDim.x + threadIdx.x;
  int s = 0;
#pragma unroll
  for (int t = 0; t < TT; ++t) s += outS[t * NN + n];
  ocnt[n] = s;
}

__device__ __forceinline__ void load_tile(const int* __restrict__ inS,
                                          const int* __restrict__ ocnt,
                                          const float* __restrict__ W,
                                          unsigned base,
                                          intx4 (&s)[TT], floatx4& w, int& o) {
#pragma unroll
  for (int t = 0; t < TT; ++t)
    s[t] = __builtin_nontemporal_load(
        reinterpret_cast<const intx4*>(inS + (size_t)t * MM + base));
  w = __builtin_nontemporal_load(reinterpret_cast<const floatx4*>(W + base));
  o = ocnt[base >> 13];
}

__device__ __forceinline__ void compute_tile(float* __restrict__ out,
                                             const unsigned* __restrict__ tbl,
                                             unsigned base,
                                             const intx4 (&s)[TT],
                                             const floatx4& w4, int o) {
  int cnt[4] = {0, 0, 0, 0};
#pragma unroll
  for (int t = 0; t < TT; ++t) {
    cnt[0] += s[t].x; cnt[1] += s[t].y; cnt[2] += s[t].z; cnt[3] += s[t].w;
  }
  const float wv[4] = {w4.x, w4.y, w4.z, w4.w};
  const bool outF = o > 0;
  float res[4];
#pragma unroll
  for (int e = 0; e < 4; ++e) {
    const unsigned j = base + (unsigned)e;
    const float w = fminf(fmaxf(wv[e], 0.0f), 8.0f);
    const int c = cnt[e];
    const bool inF = c > 0;
    const bool active = inF | outF;
    // branch index: 0=capture 1=minus 2=search 3=backoff
    // (in_t <= out_t) <=> (8-c <= 8-o) <=> (c >= o)
    const unsigned idx = inF ? (outF ? ((c >= o) ? 0u : 1u) : 2u) : 3u;

    const uintx4 r0 = *reinterpret_cast<const uintx4*>(tbl + (idx << 3));
    const uintx4 r1 = *reinterpret_cast<const uintx4*>(tbl + (idx << 3) + 4);
    const unsigned ka0 = r0.x, ka1 = r0.y, kb0 = r0.z, kb1 = r0.w;
    const unsigned kc0 = r1.x, kc1 = r1.y, thB = r1.z;
    const float sgn = __uint_as_float(r1.w);

    // p_plus / p_minus exactly as XLA (no FMA contraction)
    const float wn = w * 0.125f;
    const float pp = __fmul_rn(wn, __fsub_rn(2.0f, wn));
    const float pm = __fmul_rn(__fsub_rn(1.0f, wn), __fadd_rn(1.0f, wn));
    const float pA = (idx & 1u) ? pm : pp;   // odd rows use fminus

    unsigned a0, a1, b0, b1, c0, c1;
    tf2x32(ka0, ka1, 0u, j, a0, a1);
    const unsigned bitsA = a0 ^ a1;          // partitionable: x0 ^ x1
    const float u = __uint_as_float((bitsA >> 9) | 0x3f800000u) - 1.0f;
    const bool fab = u < pA;

    tf2x32(kb0, kb1, 0u, j, b0, b1);
    const bool gate = (((b0 ^ b1) >> 9) < thB);

    tf2x32(kc0, kc1, 0u, j, c0, c1);
    const bool um = (((c0 ^ c1) >> 9) < TH_MIN);

    const bool doit = active & gate & (fab | um);
    res[e] = doit ? __fadd_rn(w, sgn) : w;
  }
  floatx4 r;
  r.x = res[0]; r.y = res[1]; r.z = res[2]; r.w = res[3];
  __builtin_nontemporal_store(r, reinterpret_cast<floatx4*>(out + base));
}

__global__ __launch_bounds__(256) void ModSTDP_58823872086838_kernel(
    const int* __restrict__ inS,    // [T, N, S] int32 0/1
    const int* __restrict__ ocnt,   // [N] row output-spike counts (pre-kernel)
    const float* __restrict__ W,    // [N, S]
    float* __restrict__ out,        // [N, S]
    Tbl tb)
{
  __shared__ __align__(16) unsigned tbl[32];
  if (threadIdx.x < 32) tbl[threadIdx.x] = tb.v[threadIdx.x];
  __syncthreads();

  const unsigned tid = blockIdx.x * blockDim.x + threadIdx.x;
  const unsigned STRIDE = (unsigned)NTHREADS << 2;   // element stride per iter

  intx4 sA[TT], sB[TT];
  floatx4 wA, wB;
  int oA, oB;

  unsigned base = tid << 2;
  load_tile(inS, ocnt, W, base, sA, wA, oA);

#pragma unroll 1
  for (int i = 0; i < ITERS; i += 2) {
    load_tile(inS, ocnt, W, base + STRIDE, sB, wB, oB);     // issue next
    compute_tile(out, tbl, base, sA, wA, oA);               // compute cur
    if (i + 2 < ITERS)
      load_tile(inS, ocnt, W, base + 2 * STRIDE, sA, wA, oA);
    compute_tile(out, tbl, base + STRIDE, sB, wB, oB);
    base += 2 * STRIDE;
  }
}

extern "C" void kernel_launch(void* const* d_in, const int* in_sizes, int n_in,
                              void* d_out, int out_size, void* d_ws, size_t ws_size,
                              hipStream_t stream) {
  const int*   inS  = (const int*)d_in[0];
  const int*   outS = (const int*)d_in[1];
  const float* W    = (const float*)d_in[2];
  float*       out  = (float*)d_out;
  int*         ocnt = (int*)d_ws;

  // Host-side key derivation (pure arithmetic — graph-capture safe).
  // jax.random.key(42) -> (0, 42). Fold-like split (threefry_partitionable):
  // rk[i] = threefry(key, (0, i));  k7{a,b,c} = threefry(rk7, (0, {0,1,2}))
  unsigned kp[20];
  {
    unsigned rk[16];
    for (unsigned i = 0; i < 8; ++i) {
      unsigned o0, o1;
      tf2x32(0u, 42u, 0u, i, o0, o1);
      rk[2 * i] = o0; rk[2 * i + 1] = o1;
    }
    for (int i = 0; i < 14; ++i) kp[i] = rk[i];      // rk0..rk6
    for (unsigned i = 0; i < 3; ++i) {
      unsigned o0, o1;
      tf2x32(rk[14], rk[15], 0u, i, o0, o1);
      kp[14 + 2 * i] = o0; kp[15 + 2 * i] = o1;
    }
  }

  // Branch-config table rows: {ka0,ka1, kb0,kb1, kc0,kc1, thB, sgn}
  Tbl tb;
  unsigned* v = tb.v;
  // row 0: capture  — fplus, ucapture, umin1, +1
  v[0] = kp[0];  v[1] = kp[1];  v[2] = kp[4];   v[3] = kp[5];
  v[4] = kp[12]; v[5] = kp[13]; v[6] = TH_CAP10; v[7] = 0x3f800000u;
  // row 1: minus    — fminus, uminus, umin2, -1
  v[8] = kp[2];  v[9] = kp[3];  v[10] = kp[6];  v[11] = kp[7];
  v[12] = kp[14]; v[13] = kp[15]; v[14] = TH_CAP10; v[15] = 0xbf800000u;
  // row 2: search   — fplus, usearch, umin3, +1
  v[16] = kp[0]; v[17] = kp[1]; v[18] = kp[8];  v[19] = kp[9];
  v[20] = kp[16]; v[21] = kp[17]; v[22] = TH_SEARCH; v[23] = 0x3f800000u;
  // row 3: backoff  — fminus, ubackoff, umin4, -1
  v[24] = kp[2]; v[25] = kp[3]; v[26] = kp[10]; v[27] = kp[11];
  v[28] = kp[18]; v[29] = kp[19]; v[30] = TH_BACK; v[31] = 0xbf800000u;

  ModSTDP_ocnt_kernel<<<dim3(NN / 256), dim3(256), 0, stream>>>(outS, ocnt);
  ModSTDP_58823872086838_kernel<<<dim3(NBLOCKS), dim3(256), 0, stream>>>(
      inS, ocnt, W, out, tb);
}

// Round 4
// 135.246 us; speedup vs baseline: 1.0088x; 1.0088x over previous
//
#include <hip/hip_runtime.h>

#define TT 8
#define NN 2048
#define SS 8192
#define MM (NN * SS)   // 16777216 elements

// Bernoulli integer thresholds: p * 2^23 (all probabilities are dyadic k/128)
#define TH_CAP10  655360u    // 10/128 * 2^23  (ucapture, uminus)
#define TH_SEARCH 65536u     //  1/128 * 2^23
#define TH_BACK   6291456u   // 96/128 * 2^23
#define TH_MIN    262144u    //  4/128 * 2^23

#define EPT       8                      // elements per thread
#define NBLOCKS   (MM / 256 / EPT)       // 8192 blocks, one tile per thread

typedef int   __attribute__((ext_vector_type(4))) intx4;
typedef float __attribute__((ext_vector_type(4))) floatx4;
typedef unsigned __attribute__((ext_vector_type(4))) uintx4;

// 4 branch-config rows x 8 words: {ka0,ka1, kb0,kb1, kc0,kc1, thB, sgn_bits}
struct Tbl { unsigned v[32]; };

__host__ __device__ __forceinline__ void tf2x32(unsigned k0, unsigned k1,
                                                unsigned x0, unsigned x1,
                                                unsigned& o0, unsigned& o1) {
  const unsigned ks2 = k0 ^ k1 ^ 0x1BD11BDAu;
  x0 += k0; x1 += k1;
#define TFR(r) { x0 += x1; x1 = (x1 << (r)) | (x1 >> (32 - (r))); x1 ^= x0; }
  TFR(13) TFR(15) TFR(26) TFR(6)
  x0 += k1;  x1 += ks2 + 1u;
  TFR(17) TFR(29) TFR(16) TFR(24)
  x0 += ks2; x1 += k0 + 2u;
  TFR(13) TFR(15) TFR(26) TFR(6)
  x0 += k0;  x1 += k1 + 3u;
  TFR(17) TFR(29) TFR(16) TFR(24)
  x0 += k1;  x1 += ks2 + 4u;
  TFR(13) TFR(15) TFR(26) TFR(6)
  x0 += ks2; x1 += k0 + 5u;
#undef TFR
  o0 = x0; o1 = x1;
}

__global__ __launch_bounds__(256) void ModSTDP_58823872086838_kernel(
    const int* __restrict__ inS,    // [T, N, S] int32 0/1
    const int* __restrict__ outS,   // [T, N]    int32 0/1
    const float* __restrict__ W,    // [N, S]
    float* __restrict__ out,        // [N, S]
    Tbl tb)
{
  __shared__ __align__(16) unsigned tbl[32];
  if (threadIdx.x < 32) tbl[threadIdx.x] = tb.v[threadIdx.x];
  __syncthreads();

  const unsigned tid  = blockIdx.x * blockDim.x + threadIdx.x;
  const unsigned base = tid * EPT;              // 8 consecutive elements
  const unsigned n    = base >> 13;             // row (wave-uniform: 512 | 8192)

  // Row output-spike count: 8 wave-uniform loads (L1 broadcast, 64 KB table)
  int osum = 0;
#pragma unroll
  for (int t = 0; t < TT; ++t) osum += outS[t * NN + n];
  const bool outF = osum > 0;

  // Issue all 18 16-byte loads; compiler interleaves partial vmcnt waits.
  intx4 s[TT][2];
#pragma unroll
  for (int t = 0; t < TT; ++t) {
    const int* p = inS + (size_t)t * MM + base;
    s[t][0] = *reinterpret_cast<const intx4*>(p);
    s[t][1] = *reinterpret_cast<const intx4*>(p + 4);
  }
  const floatx4 w0 = *reinterpret_cast<const floatx4*>(W + base);
  const floatx4 w1 = *reinterpret_cast<const floatx4*>(W + base + 4);

  int cnt[EPT] = {0, 0, 0, 0, 0, 0, 0, 0};
#pragma unroll
  for (int t = 0; t < TT; ++t) {
#pragma unroll
    for (int e = 0; e < EPT; ++e) cnt[e] += s[t][e >> 2][e & 3];
  }

  float res[EPT];
#pragma unroll
  for (int e = 0; e < EPT; ++e) {
    const unsigned j = base + (unsigned)e;
    const float wraw = (e < 4) ? w0[e & 3] : w1[e & 3];
    const float w = fminf(fmaxf(wraw, 0.0f), 8.0f);
    const int c = cnt[e];
    const bool inF = c > 0;
    const bool active = inF | outF;
    // branch index: 0=capture 1=minus 2=search 3=backoff
    // (in_t <= out_t) <=> (8-c <= 8-o) <=> (c >= o)
    const unsigned idx = inF ? (outF ? ((c >= osum) ? 0u : 1u) : 2u) : 3u;

    const uintx4 r0 = *reinterpret_cast<const uintx4*>(tbl + (idx << 3));
    const uintx4 r1 = *reinterpret_cast<const uintx4*>(tbl + (idx << 3) + 4);
    const unsigned ka0 = r0.x, ka1 = r0.y, kb0 = r0.z, kb1 = r0.w;
    const unsigned kc0 = r1.x, kc1 = r1.y, thB = r1.z;
    const float sgn = __uint_as_float(r1.w);

    // p_plus / p_minus exactly as XLA (no FMA contraction)
    const float wn = w * 0.125f;
    const float pp = __fmul_rn(wn, __fsub_rn(2.0f, wn));
    const float pm = __fmul_rn(__fsub_rn(1.0f, wn), __fadd_rn(1.0f, wn));
    const float pA = (idx & 1u) ? pm : pp;   // odd rows use fminus

    unsigned a0, a1, b0, b1, c0, c1;
    tf2x32(ka0, ka1, 0u, j, a0, a1);
    const unsigned bitsA = a0 ^ a1;          // partitionable: x0 ^ x1
    const float u = __uint_as_float((bitsA >> 9) | 0x3f800000u) - 1.0f;
    const bool fab = u < pA;

    tf2x32(kb0, kb1, 0u, j, b0, b1);
    const bool gate = (((b0 ^ b1) >> 9) < thB);

    tf2x32(kc0, kc1, 0u, j, c0, c1);
    const bool um = (((c0 ^ c1) >> 9) < TH_MIN);

    const bool doit = active & gate & (fab | um);
    res[e] = doit ? __fadd_rn(w, sgn) : w;
  }

  floatx4 r0, r1;
  r0.x = res[0]; r0.y = res[1]; r0.z = res[2]; r0.w = res[3];
  r1.x = res[4]; r1.y = res[5]; r1.z = res[6]; r1.w = res[7];
  __builtin_nontemporal_store(r0, reinterpret_cast<floatx4*>(out + base));
  __builtin_nontemporal_store(r1, reinterpret_cast<floatx4*>(out + base + 4));
}

extern "C" void kernel_launch(void* const* d_in, const int* in_sizes, int n_in,
                              void* d_out, int out_size, void* d_ws, size_t ws_size,
                              hipStream_t stream) {
  const int*   inS  = (const int*)d_in[0];
  const int*   outS = (const int*)d_in[1];
  const float* W    = (const float*)d_in[2];
  float*       out  = (float*)d_out;

  // Host-side key derivation (pure arithmetic — graph-capture safe).
  // jax.random.key(42) -> (0, 42). Fold-like split (threefry_partitionable):
  // rk[i] = threefry(key, (0, i));  k7{a,b,c} = threefry(rk7, (0, {0,1,2}))
  unsigned kp[20];
  {
    unsigned rk[16];
    for (unsigned i = 0; i < 8; ++i) {
      unsigned o0, o1;
      tf2x32(0u, 42u, 0u, i, o0, o1);
      rk[2 * i] = o0; rk[2 * i + 1] = o1;
    }
    for (int i = 0; i < 14; ++i) kp[i] = rk[i];      // rk0..rk6
    for (unsigned i = 0; i < 3; ++i) {
      unsigned o0, o1;
      tf2x32(rk[14], rk[15], 0u, i, o0, o1);
      kp[14 + 2 * i] = o0; kp[15 + 2 * i] = o1;
    }
  }

  // Branch-config table rows: {ka0,ka1, kb0,kb1, kc0,kc1, thB, sgn}
  Tbl tb;
  unsigned* v = tb.v;
  // row 0: capture  — fplus, ucapture, umin1, +1
  v[0] = kp[0];  v[1] = kp[1];  v[2] = kp[4];   v[3] = kp[5];
  v[4] = kp[12]; v[5] = kp[13]; v[6] = TH_CAP10; v[7] = 0x3f800000u;
  // row 1: minus    — fminus, uminus, umin2, -1
  v[8] = kp[2];  v[9] = kp[3];  v[10] = kp[6];  v[11] = kp[7];
  v[12] = kp[14]; v[13] = kp[15]; v[14] = TH_CAP10; v[15] = 0xbf800000u;
  // row 2: search   — fplus, usearch, umin3, +1
  v[16] = kp[0]; v[17] = kp[1]; v[18] = kp[8];  v[19] = kp[9];
  v[20] = kp[16]; v[21] = kp[17]; v[22] = TH_SEARCH; v[23] = 0x3f800000u;
  // row 3: backoff  — fminus, ubackoff, umin4, -1
  v[24] = kp[2]; v[25] = kp[3]; v[26] = kp[10]; v[27] = kp[11];
  v[28] = kp[18]; v[29] = kp[19]; v[30] = TH_BACK; v[31] = 0xbf800000u;

  ModSTDP_58823872086838_kernel<<<dim3(NBLOCKS), dim3(256), 0, stream>>>(
      inS, outS, W, out, tb);
}